// Round 3
// baseline (211.160 us; speedup 1.0000x reference)
//
#include <hip/hip_runtime.h>

// Bicubic 4x upscale, Keys a=-0.5, jax.image.resize semantics:
// sample s = (o+0.5)/4 - 0.5; OOB taps dropped + weights renormalized.
// Phase weights (exact dyadic rationals; interior rows sum to exactly 1.0):
//   r=0: base j-2: [k(1.625), k(0.625), k(0.375), k(1.375)]
//   r=1: base j-2: [k(1.875), k(0.875), k(0.125), k(1.125)]
//   r=2/3: mirrors of r=1/0 with base j-1.
//
// Block = (bc, jy4): stages 8 input rows into guard-padded LDS (float4
// global loads -> ds_write_b128), produces 16 output rows with nontemporal
// float4 stores (output is write-once; keep it out of L2).

#define Hin 256
#define Win 256

#define WK00 -0.0439453125f
#define WK01  0.3896484375f
#define WK02  0.7275390625f
#define WK03 -0.0732421875f
#define WK10 -0.0068359375f
#define WK11  0.0908203125f
#define WK12  0.9638671875f
#define WK13 -0.0478515625f

typedef float v4f __attribute__((ext_vector_type(4)));

__global__ __launch_bounds__(256, 4) void cubic_up4(const float* __restrict__ in,
                                                    float* __restrict__ out) {
    const int jx = threadIdx.x;          // input column 0..255
    const int jy4 = blockIdx.x & 63;     // row group (4 input rows)
    const int bc = blockIdx.x >> 6;      // batch*channel 0..47
    const int jy0 = jy4 << 2;

    const float* __restrict__ inp = in + (size_t)bc * (Hin * Win);
    float* __restrict__ outp = out + (size_t)bc * ((size_t)Hin * Win * 16);

    const float WK[4][4] = {{WK00, WK01, WK02, WK03},
                            {WK10, WK11, WK12, WK13},
                            {WK13, WK12, WK11, WK10},
                            {WK03, WK02, WK01, WK00}};

    // ---- stage rows jy0-2 .. jy0+5 ----
    // Layout: data col c at sv[r][4+c]; zero guards at [0..3] and [260..263]
    // (16B-aligned so staging is ds_write_b128 / OOB taps read exact 0).
    __shared__ float sv[8][264];
    {
        const int lane = jx & 63;
        const int wv = jx >> 6;          // wave id 0..3
#pragma unroll
        for (int i = 0; i < 2; ++i) {
            const int r = wv + (i << 2);        // 0..7
            int ry = jy0 - 2 + r;
            ry = ry < 0 ? 0 : (ry > Hin - 1 ? Hin - 1 : ry);  // OOB rows: weight 0
            const v4f val = *(const v4f*)(inp + ry * Win + (lane << 2));
            *(v4f*)&sv[r][4 + (lane << 2)] = val;
        }
        if (jx < 16) {
            const v4f z = {0.f, 0.f, 0.f, 0.f};
            *(v4f*)&sv[jx & 7][(jx < 8) ? 0 : 260] = z;
        }
    }
    __syncthreads();

    // ---- horizontal pass: 8 rows x 4 phases ----
    float h[8][4];
    const bool xedge = (jx < 2) | (jx >= Win - 2);
    if (!xedge) {
#pragma unroll
        for (int r = 0; r < 8; ++r) {
            const float* p = &sv[r][jx + 2];   // p[k] = input col jx-2+k
            const float a0 = p[0], a1 = p[1], a2 = p[2], a3 = p[3], a4 = p[4];
            h[r][0] = WK00 * a0 + WK01 * a1 + WK02 * a2 + WK03 * a3;
            h[r][1] = WK10 * a0 + WK11 * a1 + WK12 * a2 + WK13 * a3;
            h[r][2] = WK13 * a1 + WK12 * a2 + WK11 * a3 + WK10 * a4;
            h[r][3] = WK03 * a1 + WK02 * a2 + WK01 * a3 + WK00 * a4;
        }
    } else {
        // edge columns: drop OOB taps, renormalize
        float wx[4][4];
#pragma unroll
        for (int r = 0; r < 4; ++r) {
            const int o = r >> 1;
            float s = 0.f;
#pragma unroll
            for (int t = 0; t < 4; ++t) {
                const int c = jx - 2 + o + t;
                const float w = (c >= 0 && c < Win) ? WK[r][t] : 0.f;
                wx[r][t] = w;
                s += w;
            }
            const float inv = __builtin_amdgcn_rcpf(s);
#pragma unroll
            for (int t = 0; t < 4; ++t) wx[r][t] *= inv;
        }
#pragma unroll
        for (int r = 0; r < 8; ++r) {
            const float* p = &sv[r][jx + 2];   // dropped taps hit zeroed guards
#pragma unroll
            for (int rx = 0; rx < 4; ++rx) {
                const int o = rx >> 1;
                h[r][rx] = wx[rx][0] * p[o] + wx[rx][1] * p[o + 1] +
                           wx[rx][2] * p[o + 2] + wx[rx][3] * p[o + 3];
            }
        }
    }

    // ---- vertical pass + nontemporal stores: 4 input rows x 4 phases ----
    const bool yedge = (jy4 == 0) | (jy4 == 63);
    if (!yedge) {
#pragma unroll
        for (int ty = 0; ty < 4; ++ty) {
#pragma unroll
            for (int ry = 0; ry < 4; ++ry) {
                const int o = ty + (ry >> 1);
                v4f res;
#pragma unroll
                for (int rx = 0; rx < 4; ++rx) {
                    res[rx] = WK[ry][0] * h[o][rx] + WK[ry][1] * h[o + 1][rx] +
                              WK[ry][2] * h[o + 2][rx] + WK[ry][3] * h[o + 3][rx];
                }
                v4f* dst = (v4f*)(outp + (size_t)((jy4 << 4) + (ty << 2) + ry) * (Win * 4) +
                                  (jx << 2));
                __builtin_nontemporal_store(res, dst);
            }
        }
    } else {
#pragma unroll
        for (int ty = 0; ty < 4; ++ty) {
            const int jy = jy0 + ty;
            float wy[4][4];
#pragma unroll
            for (int r = 0; r < 4; ++r) {
                const int o = r >> 1;
                float s = 0.f;
#pragma unroll
                for (int t = 0; t < 4; ++t) {
                    const int c = jy - 2 + o + t;
                    const float w = (c >= 0 && c < Hin) ? WK[r][t] : 0.f;
                    wy[r][t] = w;
                    s += w;
                }
                const float inv = __builtin_amdgcn_rcpf(s);
#pragma unroll
                for (int t = 0; t < 4; ++t) wy[r][t] *= inv;
            }
#pragma unroll
            for (int ry = 0; ry < 4; ++ry) {
                const int o = ty + (ry >> 1);
                v4f res;
#pragma unroll
                for (int rx = 0; rx < 4; ++rx) {
                    res[rx] = wy[ry][0] * h[o][rx] + wy[ry][1] * h[o + 1][rx] +
                              wy[ry][2] * h[o + 2][rx] + wy[ry][3] * h[o + 3][rx];
                }
                v4f* dst = (v4f*)(outp + (size_t)((jy4 << 4) + (ty << 2) + ry) * (Win * 4) +
                                  (jx << 2));
                __builtin_nontemporal_store(res, dst);
            }
        }
    }
}

extern "C" void kernel_launch(void* const* d_in, const int* in_sizes, int n_in,
                              void* d_out, int out_size, void* d_ws, size_t ws_size,
                              hipStream_t stream) {
    const float* x = (const float*)d_in[0];
    float* out = (float*)d_out;
    // 48 (b*c) * 64 row-groups = 3072 blocks, 256 threads.
    cubic_up4<<<dim3(48 * 64), dim3(256), 0, stream>>>(x, out);
}